// Round 1
// baseline (1037.425 us; speedup 1.0000x reference)
//
#include <hip/hip_runtime.h>
#include <math.h>

// ---------------------------------------------------------------------------
// ExactReactionDiffusion2D  (B=8, N=4096 (64x64), D=512, k_steps=4)
//   1. zero pooled
//   2. transpose x [B,N,D] -> xT [B,D,N]  + pooled accumulation (atomics)
//   3. gamma = min(softplus(pooled/N @ Wg^T + bg + log_base), 0.35)
//   4. per-(b,d) plane: 4x {reaction, FFT2, *phase, iFFT2, reaction}
//      (register-resident 64-pt FFTs, LDS only for row<->col transpose)
//   5. out = [re|im] @ Wout^T + x * Dparam   (f32 tiled GEMM, 128x128x8)
// ---------------------------------------------------------------------------

#define D_INNER 512
#define NTOK    4096

struct cplx { float re, im; };

__device__ __forceinline__ cplx cmul(cplx a, cplx b) {
  return { a.re * b.re - a.im * b.im, a.re * b.im + a.im * b.re };
}

// DPP quad-perm shuffles (stay on VALU pipe, no LDS)
template<int CTRL>
__device__ __forceinline__ float dppf(float x) {
  return __int_as_float(__builtin_amdgcn_mov_dpp(__float_as_int(x), CTRL, 0xf, 0xf, true));
}
#define DPP_XOR1 0xB1   // quad_perm [1,0,3,2]
#define DPP_XOR2 0x4E   // quad_perm [2,3,0,1]

// 16-point FFT, data in registers, natural-in / natural-out.
// SIGN=-1 forward (W^-nk), SIGN=+1 inverse (unnormalized).
template<int SIGN>
__device__ __forceinline__ void fft16(cplx* a) {
  const float C16[8] = {1.f, 0.9238795325112867f, 0.7071067811865476f, 0.3826834323650898f,
                        0.f, -0.3826834323650898f, -0.7071067811865476f, -0.9238795325112867f};
  const float S16[8] = {0.f, 0.3826834323650898f, 0.7071067811865476f, 0.9238795325112867f,
                        1.f, 0.9238795325112867f, 0.7071067811865476f, 0.3826834323650898f};
  cplx t;
#define SWP(i, j) { t = a[i]; a[i] = a[j]; a[j] = t; }
  SWP(1, 8) SWP(2, 4) SWP(3, 12) SWP(5, 10) SWP(7, 14) SWP(11, 13)
#undef SWP
#pragma unroll
  for (int s = 1; s <= 4; ++s) {
    const int len = 1 << s, half = len >> 1;
#pragma unroll
    for (int base = 0; base < 16; base += (1 << s)) {
#pragma unroll
      for (int j = 0; j < (1 << (s - 1)); ++j) {
        const int ti = j << (4 - s);
        const float wc = C16[ti];
        const float ws = (SIGN < 0) ? -S16[ti] : S16[ti];
        cplx u = a[base + j];
        cplx v = a[base + j + half];
        cplx vw = { v.re * wc - v.im * ws, v.re * ws + v.im * wc };
        a[base + j]        = { u.re + vw.re, u.im + vw.im };
        a[base + j + half] = { u.re - vw.re, u.im - vw.im };
      }
    }
  }
}

// Cross-quad 4-point DFT over n2 (forward, W4^-n2k2). Natural input in lanes,
// output lane b holds k2 = qmap[b] = [0,2,1,3][b].
__device__ __forceinline__ cplx fwd_cross(cplx z, bool s1, bool s2) {
  cplx w;  w.re = dppf<DPP_XOR2>(z.re);  w.im = dppf<DPP_XOR2>(z.im);
  cplx z1;
  z1.re = s2 ? (w.re - z.re) : (z.re + w.re);
  z1.im = s2 ? (w.im - z.im) : (z.im + w.im);
  cplx w2; w2.re = dppf<DPP_XOR1>(z1.re); w2.im = dppf<DPP_XOR1>(z1.im);
  cplx o;
  o.re = s1 ? (w2.re - (s2 ? z1.im : z1.re))
            : (z1.re + (s2 ? w2.im : w2.re));
  o.im = s1 ? (w2.im + (s2 ? z1.re : -z1.im))
            : (z1.im + (s2 ? -w2.re : w2.im));
  return o;
}

// Inverse 4-point DFT over k2 (W4^+n2k2). Input lane b holds k2=qmap[b],
// output natural n2 = b.
__device__ __forceinline__ cplx inv_cross(cplx z, bool s1, bool s2) {
  cplx w;  w.re = dppf<DPP_XOR1>(z.re);  w.im = dppf<DPP_XOR1>(z.im);
  cplx z1;
  z1.re = s1 ? (w.re - z.re) : (z.re + w.re);
  z1.im = s1 ? (w.im - z.im) : (z.im + w.im);
  cplx w2; w2.re = dppf<DPP_XOR2>(z1.re); w2.im = dppf<DPP_XOR2>(z1.im);
  cplx o;
  o.re = s2 ? (w2.re + (s1 ? z1.im : -z1.re))
            : (z1.re + (s1 ? -w2.im : w2.re));
  o.im = s2 ? (w2.im - (s1 ? z1.re : z1.im))
            : (z1.im + (s1 ? w2.re : w2.im));
  return o;
}

// 64-point FFT across a quad: thread holds 16 contiguous elements
// x[16*b + n1]. Forward output: reg k1 holds freq k = k2 + 4*k1 (k2=qmap[b]).
// Inverse consumes that layout, returns natural.
template<int SIGN>
__device__ __forceinline__ void fft64(cplx* a, bool s1, bool s2,
                                      const float* twc, const float* tws) {
  if (SIGN < 0) {
#pragma unroll
    for (int i = 0; i < 16; ++i) a[i] = fwd_cross(a[i], s1, s2);
#pragma unroll
    for (int i = 0; i < 16; ++i) {   // * W64^{-n1*k2}
      float c = twc[i], s = tws[i];
      cplx v = a[i];
      a[i] = { v.re * c + v.im * s, v.im * c - v.re * s };
    }
    fft16<-1>(a);
  } else {
    fft16<1>(a);
#pragma unroll
    for (int i = 0; i < 16; ++i) {   // * W64^{+n1*k2}
      float c = twc[i], s = tws[i];
      cplx v = a[i];
      a[i] = { v.re * c - v.im * s, v.im * c + v.re * s };
    }
#pragma unroll
    for (int i = 0; i < 16; ++i) a[i] = inv_cross(a[i], s1, s2);
  }
}

__device__ __forceinline__ void reaction(cplx* a, float a2, float b2, float ex,
                                         float dtr, bool a_small) {
#pragma unroll
  for (int i = 0; i < 16; ++i) {
    float q = a[i].re * a[i].re + a[i].im * a[i].im;
    float denom = fmaxf(b2 * q + (a2 - b2 * q) * ex, 1e-8f);
    float qg = a2 * q / denom;
    float qz = q / (1.f + b2 * q * dtr);
    float qn = fmaxf(a_small ? qz : qg, 0.f);
    float scale = sqrtf(qn / fmaxf(q, 1e-8f));
    a[i].re *= scale; a[i].im *= scale;
  }
}

// ---------------------------------------------------------------------------

__global__ void zero_kernel(float* p, int n) {
  int i = blockIdx.x * blockDim.x + threadIdx.x;
  if (i < n) p[i] = 0.f;
}

// x [B,N,D] -> xT [B,D,N], plus pooled[b,d] += sum_n x[b,n,d]
__global__ __launch_bounds__(256) void transpose_pool_kernel(
    const float* __restrict__ x, float* __restrict__ xT, float* __restrict__ pooled) {
  __shared__ float tile[64][65];
  const int n0 = blockIdx.x * 64, d0 = blockIdx.y * 64, b = blockIdx.z;
  const int t = threadIdx.x;
  const int tc = t & 63, tr = t >> 6;
  const float* xp = x + ((size_t)b * NTOK + n0) * D_INNER + d0;
#pragma unroll
  for (int i = 0; i < 16; ++i) {
    int nl = tr + i * 4;
    tile[nl][tc] = xp[(size_t)nl * D_INNER + tc];
  }
  __syncthreads();
  float* xo = xT + ((size_t)b * D_INNER + d0) * NTOK + n0;
#pragma unroll
  for (int i = 0; i < 16; ++i) {
    int dl = tr + i * 4;
    xo[(size_t)dl * NTOK + tc] = tile[tc][dl];
  }
  if (t < 64) {
    float s = 0.f;
#pragma unroll
    for (int n = 0; n < 64; ++n) s += tile[n][t];
    atomicAdd(&pooled[b * D_INNER + d0 + t], s);
  }
}

__global__ __launch_bounds__(256) void gamma_kernel(
    const float* __restrict__ pooled, const float* __restrict__ Wg,
    const float* __restrict__ bg, const float* __restrict__ log_base,
    float* __restrict__ gamma) {
  int t = blockIdx.x * 256 + threadIdx.x;       // 0..4095
  int b = t >> 9, j = t & 511;
  const float* pr = pooled + b * D_INNER;
  const float* wr = Wg + (size_t)j * D_INNER;
  float acc = 0.f;
#pragma unroll 4
  for (int d = 0; d < D_INNER; ++d) acc = fmaf(pr[d], wr[d], acc);
  float z = acc * (1.f / 4096.f) + bg[j] + log_base[j];
  float sp = fmaxf(z, 0.f) + log1pf(expf(-fabsf(z)));
  gamma[t] = fminf(sp, 0.35f);
}

// One 64x64 plane per block. 256 threads: rr = tid>>2 (row/col index),
// lb = tid&3 (quad sub-lane). Data in registers; LDS for transposes.
__global__ __launch_bounds__(256) void plane_kernel(
    const float* __restrict__ xT, const float* __restrict__ gamma,
    const float* __restrict__ alpha_raw, const float* __restrict__ beta_raw,
    const int* __restrict__ kstep_p,
    float* __restrict__ outRe, float* __restrict__ outIm) {
  __shared__ float2 T[64 * 65];
  __shared__ float2 P[64];
  const int blk = blockIdx.x;          // b*512 + d
  const int bb = blk >> 9, d = blk & 511;
  const int tid = threadIdx.x;
  const int lb = tid & 3;
  const int rr = tid >> 2;
  const bool s1 = lb & 1, s2 = (lb & 2) != 0;

  int ks = kstep_p[0]; if (ks < 1) ks = 1;
  const float dt  = 1.0f / (float)ks;
  const float dtr = 0.5f * dt;
  const float a2 = 2.0f * 0.25f * tanhf(alpha_raw[d]);
  float zb = beta_raw[d];
  const float b2 = 2.0f * (fmaxf(zb, 0.f) + log1pf(expf(-fabsf(zb))) + 1e-4f);
  const float ex = expf(-a2 * dtr);
  const bool a_small = fabsf(a2) < 1e-6f;
  const float cg = dt * gamma[(bb << 9) + d];

  const float TWO_PI_64 = 6.283185307179586f / 64.0f;
  if (tid < 64) {
    float e = 2.0f * cosf(TWO_PI_64 * (float)tid) - 2.0f;
    float sv, cv; sincosf(cg * e, &sv, &cv);
    P[tid] = make_float2(cv * 0.015625f, sv * 0.015625f);   // 1/64 per dim
  }
  const int k2 = (lb == 1) ? 2 : ((lb == 2) ? 1 : lb);      // qmap[lb]
  float twc[16], tws[16];
#pragma unroll
  for (int i = 0; i < 16; ++i) sincosf(TWO_PI_64 * (float)(i * k2), &tws[i], &twc[i]);

  cplx a[16];
  const float* px = xT + (size_t)blk * NTOK + rr * 64 + lb * 16;
#pragma unroll
  for (int i = 0; i < 4; ++i) {
    float4 v = *(const float4*)(px + i * 4);
    a[i*4+0] = { v.x, 0.f }; a[i*4+1] = { v.y, 0.f };
    a[i*4+2] = { v.z, 0.f }; a[i*4+3] = { v.w, 0.f };
  }
  __syncthreads();   // P ready

  for (int step = 0; step < ks; ++step) {
    reaction(a, a2, b2, ex, dtr, a_small);
    fft64<-1>(a, s1, s2, twc, tws);                 // row FFT
    __syncthreads();
#pragma unroll
    for (int i = 0; i < 16; ++i)                    // store at true kx
      T[rr * 65 + (k2 + 4 * i)] = make_float2(a[i].re, a[i].im);
    __syncthreads();
#pragma unroll
    for (int i = 0; i < 16; ++i) {                  // col layout, natural y
      float2 v = T[(lb * 16 + i) * 65 + rr];
      a[i] = { v.x, v.y };
    }
    fft64<-1>(a, s1, s2, twc, tws);                 // col FFT
    {
      float2 pc = P[rr];                            // kx = rr
      cplx pcc = { pc.x, pc.y };
#pragma unroll
      for (int i = 0; i < 16; ++i) {                // ky = k2 + 4*i
        float2 pk = P[k2 + 4 * i];
        a[i] = cmul(a[i], cmul({pk.x, pk.y}, pcc));
      }
    }
    fft64<1>(a, s1, s2, twc, tws);                  // col inverse -> natural y
    __syncthreads();
#pragma unroll
    for (int i = 0; i < 16; ++i)
      T[(lb * 16 + i) * 65 + rr] = make_float2(a[i].re, a[i].im);
    __syncthreads();
#pragma unroll
    for (int i = 0; i < 16; ++i) {                  // row layout, scrambled kx
      float2 v = T[rr * 65 + (k2 + 4 * i)];
      a[i] = { v.x, v.y };
    }
    fft64<1>(a, s1, s2, twc, tws);                  // row inverse -> natural x
    reaction(a, a2, b2, ex, dtr, a_small);
  }

  float* pre = outRe + (size_t)blk * NTOK + rr * 64 + lb * 16;
  float* pim = outIm + (size_t)blk * NTOK + rr * 64 + lb * 16;
#pragma unroll
  for (int i = 0; i < 4; ++i) {
    float4 vr = { a[i*4+0].re, a[i*4+1].re, a[i*4+2].re, a[i*4+3].re };
    float4 vi = { a[i*4+0].im, a[i*4+1].im, a[i*4+2].im, a[i*4+3].im };
    *(float4*)(pre + i * 4) = vr;
    *(float4*)(pim + i * 4) = vi;
  }
}

// out[b,n,j] = sum_k W[j,k]*S[b,k,n] + x[b,n,j]*Dp[j]
// S: k<512 -> Re plane, k>=512 -> Im plane. Tiles 128(n) x 128(j), BK=8.
__global__ __launch_bounds__(256) void out_gemm_kernel(
    const float* __restrict__ Re, const float* __restrict__ Im,
    const float* __restrict__ Wout, const float* __restrict__ x,
    const float* __restrict__ Dp, float* __restrict__ out) {
  __shared__ float Wt[8][132];
  __shared__ float Bt[8][132];
  const int n0 = blockIdx.x * 128, j0 = blockIdx.y * 128, b = blockIdx.z;
  const int t = threadIdx.x;
  const int tx = t & 15, ty = t >> 4;       // tx -> j, ty -> n
  float acc[8][8];
#pragma unroll
  for (int i = 0; i < 8; ++i)
#pragma unroll
    for (int j = 0; j < 8; ++j) acc[i][j] = 0.f;
  const size_t plane = (size_t)b * D_INNER * NTOK;

  for (int k0 = 0; k0 < 1024; k0 += 8) {
    {
      int jj = t >> 1, kk = (t & 1) * 4;
      float4 v = *(const float4*)&Wout[(size_t)(j0 + jj) * 1024 + k0 + kk];
      Wt[kk + 0][jj] = v.x; Wt[kk + 1][jj] = v.y;
      Wt[kk + 2][jj] = v.z; Wt[kk + 3][jj] = v.w;
    }
    {
      int kk = t >> 5, nn = (t & 31) * 4;
      int kg = k0 + kk;
      const float* src = (kg < 512) ? (Re + plane + (size_t)kg * NTOK + n0)
                                    : (Im + plane + (size_t)(kg - 512) * NTOK + n0);
      *(float4*)&Bt[kk][nn] = *(const float4*)&src[nn];
    }
    __syncthreads();
#pragma unroll
    for (int kk = 0; kk < 8; ++kk) {
      float aj[8], bn[8];
      *(float4*)&aj[0] = *(const float4*)&Wt[kk][tx * 8];
      *(float4*)&aj[4] = *(const float4*)&Wt[kk][tx * 8 + 4];
      *(float4*)&bn[0] = *(const float4*)&Bt[kk][ty * 8];
      *(float4*)&bn[4] = *(const float4*)&Bt[kk][ty * 8 + 4];
#pragma unroll
      for (int i = 0; i < 8; ++i)
#pragma unroll
        for (int j = 0; j < 8; ++j)
          acc[i][j] = fmaf(bn[i], aj[j], acc[i][j]);
    }
    __syncthreads();
  }

  float dp[8];
#pragma unroll
  for (int j = 0; j < 8; ++j) dp[j] = Dp[j0 + tx * 8 + j];
#pragma unroll
  for (int i = 0; i < 8; ++i) {
    int n = n0 + ty * 8 + i;
    const float* xrow = x + ((size_t)b * NTOK + n) * D_INNER + j0 + tx * 8;
    float* orow = out + ((size_t)b * NTOK + n) * D_INNER + j0 + tx * 8;
    float4 o0, o1;
    float4 x0 = *(const float4*)&xrow[0];
    float4 x1 = *(const float4*)&xrow[4];
    o0.x = acc[i][0] + x0.x * dp[0]; o0.y = acc[i][1] + x0.y * dp[1];
    o0.z = acc[i][2] + x0.z * dp[2]; o0.w = acc[i][3] + x0.w * dp[3];
    o1.x = acc[i][4] + x1.x * dp[4]; o1.y = acc[i][5] + x1.y * dp[5];
    o1.z = acc[i][6] + x1.z * dp[6]; o1.w = acc[i][7] + x1.w * dp[7];
    *(float4*)&orow[0] = o0;
    *(float4*)&orow[4] = o1;
  }
}

// ---------------------------------------------------------------------------

extern "C" void kernel_launch(void* const* d_in, const int* in_sizes, int n_in,
                              void* d_out, int out_size, void* d_ws, size_t ws_size,
                              hipStream_t stream) {
  const float* x         = (const float*)d_in[0];
  const float* Wg        = (const float*)d_in[1];
  const float* bg        = (const float*)d_in[2];
  const float* log_base  = (const float*)d_in[3];
  const float* alpha_raw = (const float*)d_in[4];
  const float* beta_raw  = (const float*)d_in[5];
  const float* Wout      = (const float*)d_in[6];
  const float* Dparam    = (const float*)d_in[7];
  const int*   kstep     = (const int*)d_in[8];
  float* out = (float*)d_out;

  char* ws = (char*)d_ws;
  const size_t PLANE_BYTES = (size_t)8 * D_INNER * NTOK * sizeof(float);  // 64 MB
  float* xT     = (float*)ws;                            // [B,512,4096] re (in-place)
  float* ImBuf  = (float*)(ws + PLANE_BYTES);            // [B,512,4096] im
  float* pooled = (float*)(ws + 2 * PLANE_BYTES);        // [B,512]
  float* gamma  = pooled + 8 * D_INNER;                  // [B,512]

  zero_kernel<<<16, 256, 0, stream>>>(pooled, 8 * D_INNER);
  transpose_pool_kernel<<<dim3(64, 8, 8), 256, 0, stream>>>(x, xT, pooled);
  gamma_kernel<<<16, 256, 0, stream>>>(pooled, Wg, bg, log_base, gamma);
  plane_kernel<<<4096, 256, 0, stream>>>(xT, gamma, alpha_raw, beta_raw, kstep, xT, ImBuf);
  out_gemm_kernel<<<dim3(32, 4, 8), 256, 0, stream>>>(xT, ImBuf, Wout, x, Dparam, out);
}

// Round 3
// 505.270 us; speedup vs baseline: 2.0532x; 2.0532x over previous
//
#include <hip/hip_runtime.h>
#include <math.h>

// ---------------------------------------------------------------------------
// ExactReactionDiffusion2D  (B=8, N=4096 (64x64), D=512, k_steps=4)
//   zero pooled -> transpose+pool -> gamma
//   plane: per (b,d): zero-plane shortcut (a2 <= -1e-6 provably zeroes psi),
//          else 4x {fast-reaction, FFT2, *phase, iFFT2, fast-reaction};
//          writes S fp16 planes [b][k][n] (k=d: Re, k=512+d: Im)
//   transpose_S: S[b][k][n] -> S_T[b][n][k] (fp16, LDS tiles, overlays xT)
//   gemm: out = S_T @ Wout^T + x*Dp  via mfma_f32_16x16x32_f16, 128x128x32
// ---------------------------------------------------------------------------

#define D_INNER 512
#define NTOK    4096

typedef _Float16 half8 __attribute__((ext_vector_type(8)));
typedef float    f32x4 __attribute__((ext_vector_type(4)));

struct cplx { float re, im; };

__device__ __forceinline__ cplx cmul(cplx a, cplx b) {
  return { a.re * b.re - a.im * b.im, a.re * b.im + a.im * b.re };
}

template<int CTRL>
__device__ __forceinline__ float dppf(float x) {
  return __int_as_float(__builtin_amdgcn_mov_dpp(__float_as_int(x), CTRL, 0xf, 0xf, true));
}
#define DPP_XOR1 0xB1   // quad_perm [1,0,3,2]
#define DPP_XOR2 0x4E   // quad_perm [2,3,0,1]

template<int SIGN>
__device__ __forceinline__ void fft16(cplx* a) {
  const float C16[8] = {1.f, 0.9238795325112867f, 0.7071067811865476f, 0.3826834323650898f,
                        0.f, -0.3826834323650898f, -0.7071067811865476f, -0.9238795325112867f};
  const float S16[8] = {0.f, 0.3826834323650898f, 0.7071067811865476f, 0.9238795325112867f,
                        1.f, 0.9238795325112867f, 0.7071067811865476f, 0.3826834323650898f};
  cplx t;
#define SWP(i, j) { t = a[i]; a[i] = a[j]; a[j] = t; }
  SWP(1, 8) SWP(2, 4) SWP(3, 12) SWP(5, 10) SWP(7, 14) SWP(11, 13)
#undef SWP
#pragma unroll
  for (int s = 1; s <= 4; ++s) {
    const int half = 1 << (s - 1);
#pragma unroll
    for (int base = 0; base < 16; base += (1 << s)) {
#pragma unroll
      for (int j = 0; j < (1 << (s - 1)); ++j) {
        const int ti = j << (4 - s);
        const float wc = C16[ti];
        const float ws = (SIGN < 0) ? -S16[ti] : S16[ti];
        cplx u = a[base + j];
        cplx v = a[base + j + half];
        cplx vw = { v.re * wc - v.im * ws, v.re * ws + v.im * wc };
        a[base + j]        = { u.re + vw.re, u.im + vw.im };
        a[base + j + half] = { u.re - vw.re, u.im - vw.im };
      }
    }
  }
}

__device__ __forceinline__ cplx fwd_cross(cplx z, bool s1, bool s2) {
  cplx w;  w.re = dppf<DPP_XOR2>(z.re);  w.im = dppf<DPP_XOR2>(z.im);
  cplx z1;
  z1.re = s2 ? (w.re - z.re) : (z.re + w.re);
  z1.im = s2 ? (w.im - z.im) : (z.im + w.im);
  cplx w2; w2.re = dppf<DPP_XOR1>(z1.re); w2.im = dppf<DPP_XOR1>(z1.im);
  cplx o;
  o.re = s1 ? (w2.re - (s2 ? z1.im : z1.re))
            : (z1.re + (s2 ? w2.im : w2.re));
  o.im = s1 ? (w2.im + (s2 ? z1.re : -z1.im))
            : (z1.im + (s2 ? -w2.re : w2.im));
  return o;
}

__device__ __forceinline__ cplx inv_cross(cplx z, bool s1, bool s2) {
  cplx w;  w.re = dppf<DPP_XOR1>(z.re);  w.im = dppf<DPP_XOR1>(z.im);
  cplx z1;
  z1.re = s1 ? (w.re - z.re) : (z.re + w.re);
  z1.im = s1 ? (w.im - z.im) : (z.im + w.im);
  cplx w2; w2.re = dppf<DPP_XOR2>(z1.re); w2.im = dppf<DPP_XOR2>(z1.im);
  cplx o;
  o.re = s2 ? (w2.re + (s1 ? z1.im : -z1.re))
            : (z1.re + (s1 ? -w2.im : w2.re));
  o.im = s2 ? (w2.im - (s1 ? z1.re : z1.im))
            : (z1.im + (s1 ? w2.re : w2.im));
  return o;
}

template<int SIGN>
__device__ __forceinline__ void fft64(cplx* a, bool s1, bool s2,
                                      const float* twc, const float* tws) {
  if (SIGN < 0) {
#pragma unroll
    for (int i = 0; i < 16; ++i) a[i] = fwd_cross(a[i], s1, s2);
#pragma unroll
    for (int i = 0; i < 16; ++i) {
      float c = twc[i], s = tws[i];
      cplx v = a[i];
      a[i] = { v.re * c + v.im * s, v.im * c - v.re * s };
    }
    fft16<-1>(a);
  } else {
    fft16<1>(a);
#pragma unroll
    for (int i = 0; i < 16; ++i) {
      float c = twc[i], s = tws[i];
      cplx v = a[i];
      a[i] = { v.re * c - v.im * s, v.im * c + v.re * s };
    }
#pragma unroll
    for (int i = 0; i < 16; ++i) a[i] = inv_cross(a[i], s1, s2);
  }
}

// scale = sA * rsqrt(cB*q + cC)  — algebraic reduction of the exact-logistic
// rescale (qn/q cancels); valid for the a2 > -1e-6 branches.
__device__ __forceinline__ void reaction_fast(cplx* a, float sA, float cB, float cC) {
#pragma unroll
  for (int i = 0; i < 16; ++i) {
    float q = fmaf(a[i].re, a[i].re, a[i].im * a[i].im);
    float s = sA * rsqrtf(fmaf(cB, q, cC));
    a[i].re *= s; a[i].im *= s;
  }
}

// ---------------------------------------------------------------------------

__global__ void zero_kernel(float* p, int n) {
  int i = blockIdx.x * blockDim.x + threadIdx.x;
  if (i < n) p[i] = 0.f;
}

__global__ __launch_bounds__(256) void transpose_pool_kernel(
    const float* __restrict__ x, float* __restrict__ xT, float* __restrict__ pooled) {
  __shared__ float tile[64][65];
  const int n0 = blockIdx.x * 64, d0 = blockIdx.y * 64, b = blockIdx.z;
  const int t = threadIdx.x;
  const int tc = t & 63, tr = t >> 6;
  const float* xp = x + ((size_t)b * NTOK + n0) * D_INNER + d0;
#pragma unroll
  for (int i = 0; i < 16; ++i) {
    int nl = tr + i * 4;
    tile[nl][tc] = xp[(size_t)nl * D_INNER + tc];
  }
  __syncthreads();
  float* xo = xT + ((size_t)b * D_INNER + d0) * NTOK + n0;
#pragma unroll
  for (int i = 0; i < 16; ++i) {
    int dl = tr + i * 4;
    xo[(size_t)dl * NTOK + tc] = tile[tc][dl];
  }
  if (t < 64) {
    float s = 0.f;
#pragma unroll
    for (int n = 0; n < 64; ++n) s += tile[n][t];
    atomicAdd(&pooled[b * D_INNER + d0 + t], s);
  }
}

__global__ __launch_bounds__(256) void gamma_kernel(
    const float* __restrict__ pooled, const float* __restrict__ Wg,
    const float* __restrict__ bg, const float* __restrict__ log_base,
    float* __restrict__ gamma) {
  int t = blockIdx.x * 256 + threadIdx.x;       // 0..4095
  int b = t >> 9, j = t & 511;
  const float* pr = pooled + b * D_INNER;
  const float* wr = Wg + (size_t)j * D_INNER;
  float acc = 0.f;
#pragma unroll 4
  for (int d = 0; d < D_INNER; ++d) acc = fmaf(pr[d], wr[d], acc);
  float z = acc * (1.f / 4096.f) + bg[j] + log_base[j];
  float sp = fmaxf(z, 0.f) + log1pf(expf(-fabsf(z)));
  gamma[t] = fminf(sp, 0.35f);
}

// One 64x64 plane per block. Outputs fp16 planes S[b][k][n], k=d Re, 512+d Im.
__global__ __launch_bounds__(256) void plane_kernel(
    const float* __restrict__ xT, const float* __restrict__ gamma,
    const float* __restrict__ alpha_raw, const float* __restrict__ beta_raw,
    const int* __restrict__ kstep_p, _Float16* __restrict__ S) {
  __shared__ float2 T[64 * 65];
  __shared__ float2 P[64];
  const int blk = blockIdx.x;          // b*512 + d
  const int bb = blk >> 9, d = blk & 511;
  const int tid = threadIdx.x;
  const int lb = tid & 3;
  const int rr = tid >> 2;
  const bool s1 = lb & 1, s2 = (lb & 2) != 0;

  int ks = kstep_p[0]; if (ks < 1) ks = 1;
  const float dt  = 1.0f / (float)ks;
  const float dtr = 0.5f * dt;
  const float a2 = 2.0f * 0.25f * tanhf(alpha_raw[d]);
  float zb = beta_raw[d];
  const float b2 = 2.0f * (fmaxf(zb, 0.f) + log1pf(expf(-fabsf(zb))) + 1e-4f);

  _Float16* Sre = S + ((size_t)(bb * 1024 + d)) * NTOK + rr * 64 + lb * 16;
  _Float16* Sim = S + ((size_t)(bb * 1024 + 512 + d)) * NTOK + rr * 64 + lb * 16;

  // Provably-zero channels: a2 <= -1e-6 -> denom<0 -> clamp -> q_new=0 -> psi=0.
  if (a2 <= -1e-6f) {
    half8 z = {};
    *(half8*)&Sre[0] = z; *(half8*)&Sre[8] = z;
    *(half8*)&Sim[0] = z; *(half8*)&Sim[8] = z;
    return;
  }

  float sA, cB, cC;
  if (a2 < 1e-6f) {           // |a2| < 1e-6: q_zero_alpha path
    sA = 1.f; cB = b2 * dtr; cC = 1.f;
  } else {                    // a2 >= 1e-6: denom always positive, no clamp
    float ex = expf(-a2 * dtr);
    sA = sqrtf(a2); cB = b2 * (1.f - ex); cC = a2 * ex;
  }
  const float cg = dt * gamma[(bb << 9) + d];

  const float TWO_PI_64 = 6.283185307179586f / 64.0f;
  if (tid < 64) {
    float e = 2.0f * cosf(TWO_PI_64 * (float)tid) - 2.0f;
    float sv, cv; sincosf(cg * e, &sv, &cv);
    P[tid] = make_float2(cv * 0.015625f, sv * 0.015625f);   // 1/64 per dim
  }
  const int k2 = (lb == 1) ? 2 : ((lb == 2) ? 1 : lb);      // qmap[lb]
  float twc[16], tws[16];
  {
    float c1, s1v; sincosf(TWO_PI_64 * (float)k2, &s1v, &c1);
    twc[0] = 1.f; tws[0] = 0.f;
#pragma unroll
    for (int i = 1; i < 16; ++i) {
      float pc = twc[i-1], ps = tws[i-1];
      twc[i] = pc * c1 - ps * s1v;
      tws[i] = ps * c1 + pc * s1v;
    }
  }

  cplx a[16];
  const float* px = xT + (size_t)blk * NTOK + rr * 64 + lb * 16;
#pragma unroll
  for (int i = 0; i < 4; ++i) {
    float4 v = *(const float4*)(px + i * 4);
    a[i*4+0] = { v.x, 0.f }; a[i*4+1] = { v.y, 0.f };
    a[i*4+2] = { v.z, 0.f }; a[i*4+3] = { v.w, 0.f };
  }
  __syncthreads();   // P ready

  for (int step = 0; step < ks; ++step) {
    reaction_fast(a, sA, cB, cC);
    fft64<-1>(a, s1, s2, twc, tws);                 // row FFT
    __syncthreads();
#pragma unroll
    for (int i = 0; i < 16; ++i)
      T[rr * 65 + (k2 + 4 * i)] = make_float2(a[i].re, a[i].im);
    __syncthreads();
#pragma unroll
    for (int i = 0; i < 16; ++i) {
      float2 v = T[(lb * 16 + i) * 65 + rr];
      a[i] = { v.x, v.y };
    }
    fft64<-1>(a, s1, s2, twc, tws);                 // col FFT
    {
      float2 pc = P[rr];
      cplx pcc = { pc.x, pc.y };
#pragma unroll
      for (int i = 0; i < 16; ++i) {
        float2 pk = P[k2 + 4 * i];
        a[i] = cmul(a[i], cmul({pk.x, pk.y}, pcc));
      }
    }
    fft64<1>(a, s1, s2, twc, tws);                  // col inverse
    __syncthreads();
#pragma unroll
    for (int i = 0; i < 16; ++i)
      T[(lb * 16 + i) * 65 + rr] = make_float2(a[i].re, a[i].im);
    __syncthreads();
#pragma unroll
    for (int i = 0; i < 16; ++i) {
      float2 v = T[rr * 65 + (k2 + 4 * i)];
      a[i] = { v.x, v.y };
    }
    fft64<1>(a, s1, s2, twc, tws);                  // row inverse
    reaction_fast(a, sA, cB, cC);
  }

  half8 hr0, hr1, hi0, hi1;
#pragma unroll
  for (int i = 0; i < 8; ++i) {
    hr0[i] = (_Float16)a[i].re;     hi0[i] = (_Float16)a[i].im;
    hr1[i] = (_Float16)a[8+i].re;   hi1[i] = (_Float16)a[8+i].im;
  }
  *(half8*)&Sre[0] = hr0; *(half8*)&Sre[8] = hr1;
  *(half8*)&Sim[0] = hi0; *(half8*)&Sim[8] = hi1;
}

// S[b][k][n] -> S_T[b][n][k], 64x64 fp16 tiles, XOR-swizzled LDS.
__global__ __launch_bounds__(256) void transpose_S_kernel(
    const _Float16* __restrict__ S, _Float16* __restrict__ ST) {
  __shared__ __attribute__((aligned(16))) _Float16 tile[64 * 64];
  const int n0 = blockIdx.x * 64, k0 = blockIdx.y * 64, b = blockIdx.z;
  const int t = threadIdx.x;
#pragma unroll
  for (int r = 0; r < 2; ++r) {
    int idx = r * 256 + t, kr = idx >> 3, c = idx & 7;
    half8 v = *(const half8*)&S[((size_t)b * 1024 + k0 + kr) * NTOK + n0 + c * 8];
    *(half8*)&tile[kr * 64 + ((c ^ (kr & 7)) * 8)] = v;
  }
  __syncthreads();
#pragma unroll
  for (int r = 0; r < 2; ++r) {
    int idx = r * 256 + t, nr = idx >> 3, ck = idx & 7;
    half8 v;
#pragma unroll
    for (int j = 0; j < 8; ++j) {
      int k = ck * 8 + j;
      v[j] = tile[k * 64 + (((nr >> 3) ^ (k & 7)) * 8) + (nr & 7)];
    }
    *(half8*)&ST[((size_t)b * NTOK + n0 + nr) * 1024 + k0 + ck * 8] = v;
  }
}

// out[b,n,j] = sum_k W[j,k]*ST[b,n,k] + x[b,n,j]*Dp[j]
// 128n x 128j tile, BK=32, fp16 MFMA 16x16x32, reg-staged LDS w/ XOR swizzle.
__global__ __launch_bounds__(256) void out_gemm_f16(
    const _Float16* __restrict__ ST, const float* __restrict__ Wout,
    const float* __restrict__ x, const float* __restrict__ Dp,
    float* __restrict__ out) {
  __shared__ __attribute__((aligned(16))) _Float16 Abuf[2][128 * 32];  // W [j][k]
  __shared__ __attribute__((aligned(16))) _Float16 Bbuf[2][128 * 32];  // S [n][k]
  const int t = threadIdx.x;
  const int n0 = blockIdx.x * 128, j0 = blockIdx.y * 128, b = blockIdx.z;
  const int w = t >> 6, l = t & 63;
  const int jw = (w & 1) * 64, nw = (w >> 1) * 64;
  const int l15 = l & 15, l4 = l >> 4;

  const int sr = t >> 1, skh = t & 1;   // A staging: row, k-half
  const int br_ = t >> 2, bc = t & 3;   // B staging: row base, chunk
  const _Float16* Sb = ST + (size_t)b * NTOK * 1024;

  float aReg[16];
  half8 bReg0, bReg1;

  auto loadA = [&](int k0) {
    const float* src = Wout + (size_t)(j0 + sr) * 1024 + k0 + skh * 16;
    *(float4*)&aReg[0]  = *(const float4*)&src[0];
    *(float4*)&aReg[4]  = *(const float4*)&src[4];
    *(float4*)&aReg[8]  = *(const float4*)&src[8];
    *(float4*)&aReg[12] = *(const float4*)&src[12];
  };
  auto loadB = [&](int k0) {
    bReg0 = *(const half8*)&Sb[(size_t)(n0 + br_) * 1024 + k0 + bc * 8];
    bReg1 = *(const half8*)&Sb[(size_t)(n0 + 64 + br_) * 1024 + k0 + bc * 8];
  };
  auto writeA = [&](int buf) {
    half8 h0, h1;
#pragma unroll
    for (int i = 0; i < 8; ++i) { h0[i] = (_Float16)aReg[i]; h1[i] = (_Float16)aReg[8 + i]; }
    int c0 = skh * 2, c1 = skh * 2 + 1, s = (sr >> 1) & 3;
    *(half8*)&Abuf[buf][sr * 32 + ((c0 ^ s) * 8)] = h0;
    *(half8*)&Abuf[buf][sr * 32 + ((c1 ^ s) * 8)] = h1;
  };
  auto writeB = [&](int buf) {
    int r0 = br_, r1 = 64 + br_;
    *(half8*)&Bbuf[buf][r0 * 32 + ((bc ^ ((r0 >> 1) & 3)) * 8)] = bReg0;
    *(half8*)&Bbuf[buf][r1 * 32 + ((bc ^ ((r1 >> 1) & 3)) * 8)] = bReg1;
  };

  f32x4 acc[4][4] = {};
  loadA(0); loadB(0);
  writeA(0); writeB(0);
  __syncthreads();
  int cur = 0;
  for (int kt = 0; kt < 32; ++kt) {
    if (kt + 1 < 32) { loadA((kt + 1) * 32); loadB((kt + 1) * 32); }
    half8 af[4], bf[4];
#pragma unroll
    for (int ff = 0; ff < 4; ++ff) {
      int jr = jw + ff * 16 + l15;
      af[ff] = *(const half8*)&Abuf[cur][jr * 32 + (((l4 ^ (jr >> 1)) & 3) * 8)];
      int nr = nw + ff * 16 + l15;
      bf[ff] = *(const half8*)&Bbuf[cur][nr * 32 + (((l4 ^ (nr >> 1)) & 3) * 8)];
    }
#pragma unroll
    for (int jf = 0; jf < 4; ++jf)
#pragma unroll
      for (int nf = 0; nf < 4; ++nf)
        acc[jf][nf] = __builtin_amdgcn_mfma_f32_16x16x32_f16(af[jf], bf[nf], acc[jf][nf], 0, 0, 0);
    if (kt + 1 < 32) {
      cur ^= 1;
      writeA(cur); writeB(cur);
      __syncthreads();
    }
  }

#pragma unroll
  for (int jf = 0; jf < 4; ++jf) {
#pragma unroll
    for (int nf = 0; nf < 4; ++nf) {
      int jr4 = j0 + jw + jf * 16 + l4 * 4;
      int n   = n0 + nw + nf * 16 + l15;
      const float* xrow = x + ((size_t)b * NTOK + n) * D_INNER + jr4;
      float* orow = out + ((size_t)b * NTOK + n) * D_INNER + jr4;
      float4 xv = *(const float4*)xrow;
      float4 dv = *(const float4*)&Dp[jr4];
      float4 o;
      o.x = acc[jf][nf][0] + xv.x * dv.x;
      o.y = acc[jf][nf][1] + xv.y * dv.y;
      o.z = acc[jf][nf][2] + xv.z * dv.z;
      o.w = acc[jf][nf][3] + xv.w * dv.w;
      *(float4*)orow = o;
    }
  }
}

// ---------------------------------------------------------------------------

extern "C" void kernel_launch(void* const* d_in, const int* in_sizes, int n_in,
                              void* d_out, int out_size, void* d_ws, size_t ws_size,
                              hipStream_t stream) {
  const float* x         = (const float*)d_in[0];
  const float* Wg        = (const float*)d_in[1];
  const float* bg        = (const float*)d_in[2];
  const float* log_base  = (const float*)d_in[3];
  const float* alpha_raw = (const float*)d_in[4];
  const float* beta_raw  = (const float*)d_in[5];
  const float* Wout      = (const float*)d_in[6];
  const float* Dparam    = (const float*)d_in[7];
  const int*   kstep     = (const int*)d_in[8];
  float* out = (float*)d_out;

  char* ws = (char*)d_ws;
  float*    xT = (float*)ws;                          // [B,512,4096] f32, 64 MiB
  _Float16* S  = (_Float16*)(ws + 67108864);          // [B,1024,4096] fp16, 64 MiB
  _Float16* STr = (_Float16*)ws;                      // [B,4096,1024] fp16, overlays xT
  float* pooled = (float*)(ws + 134217728);           // [B,512]
  float* gamma  = pooled + 8 * D_INNER;               // [B,512]

  zero_kernel<<<16, 256, 0, stream>>>(pooled, 8 * D_INNER);
  transpose_pool_kernel<<<dim3(64, 8, 8), 256, 0, stream>>>(x, xT, pooled);
  gamma_kernel<<<16, 256, 0, stream>>>(pooled, Wg, bg, log_base, gamma);
  plane_kernel<<<4096, 256, 0, stream>>>(xT, gamma, alpha_raw, beta_raw, kstep, S);
  transpose_S_kernel<<<dim3(64, 16, 8), 256, 0, stream>>>(S, STr);
  out_gemm_f16<<<dim3(32, 4, 8), 256, 0, stream>>>(STr, Wout, x, Dparam, out);
}

// Round 6
// 457.382 us; speedup vs baseline: 2.2682x; 1.1047x over previous
//
#include <hip/hip_runtime.h>
#include <math.h>

// ---------------------------------------------------------------------------
// ExactReactionDiffusion2D  (B=8, N=4096 (64x64), D=512, k_steps=4)
//   zero pooled -> transpose+pool -> gamma -> convert W to fp16
//   plane: zero shortcut (a2<=-1e-6); else react(dt/2), k x [FFT2,phase,iFFT2]
//          with react(dt) between (exact flow composition), react(dt/2).
//          Complex math on float2 ext-vectors -> v_pk_*_f32 packed ops.
//   transpose_S: S[b][k][n] -> S_T[b][n][k] fp16
//   gemm: out = S_T @ Wh^T + x*Dp; mfma 16x16x32 f16, global_load_lds,
//         2-phase double-buffer, 1 barrier per K-step.
// ---------------------------------------------------------------------------

#define D_INNER 512
#define NTOK    4096

typedef _Float16 half8 __attribute__((ext_vector_type(8)));
typedef float    f32x4 __attribute__((ext_vector_type(4)));
typedef float    f32x2 __attribute__((ext_vector_type(2)));

#define DPP_XOR1 0xB1   // quad_perm [1,0,3,2]
#define DPP_XOR2 0x4E   // quad_perm [2,3,0,1]

template<int CTRL>
__device__ __forceinline__ float dppf(float x) {
  return __int_as_float(__builtin_amdgcn_mov_dpp(__float_as_int(x), CTRL, 0xf, 0xf, true));
}
template<int CTRL>
__device__ __forceinline__ f32x2 dpp2(f32x2 v) {
  f32x2 r;
  r.x = dppf<CTRL>(v.x);
  r.y = dppf<CTRL>(v.y);
  return r;
}
__device__ __forceinline__ f32x2 cswap(f32x2 v) { return __builtin_shufflevector(v, v, 1, 0); }

// full complex multiply a*b
__device__ __forceinline__ f32x2 cmulv(f32x2 a, f32x2 b) {
  f32x2 ar = __builtin_shufflevector(a, a, 0, 0);
  f32x2 ai = __builtin_shufflevector(a, a, 1, 1);
  f32x2 bs = cswap(b) * (f32x2){-1.f, 1.f};
  return ar * b + ai * bs;
}

// 16-point FFT in registers, natural-in/out. SIGN=-1 fwd, +1 inverse.
template<int SIGN>
__device__ __forceinline__ void fft16v(f32x2* a) {
  const float C16[8] = {1.f, 0.9238795325112867f, 0.7071067811865476f, 0.3826834323650898f,
                        0.f, -0.3826834323650898f, -0.7071067811865476f, -0.9238795325112867f};
  const float S16[8] = {0.f, 0.3826834323650898f, 0.7071067811865476f, 0.9238795325112867f,
                        1.f, 0.9238795325112867f, 0.7071067811865476f, 0.3826834323650898f};
  f32x2 t;
#define SWP(i, j) { t = a[i]; a[i] = a[j]; a[j] = t; }
  SWP(1, 8) SWP(2, 4) SWP(3, 12) SWP(5, 10) SWP(7, 14) SWP(11, 13)
#undef SWP
#pragma unroll
  for (int s = 1; s <= 4; ++s) {
    const int half = 1 << (s - 1);
#pragma unroll
    for (int base = 0; base < 16; base += (1 << s)) {
#pragma unroll
      for (int j = 0; j < half; ++j) {
        const int ti = j << (4 - s);
        const float wc = C16[ti];
        const float wsv = (SIGN < 0) ? -S16[ti] : S16[ti];
        f32x2 u = a[base + j];
        f32x2 v = a[base + j + half];
        f32x2 vw = v * (f32x2){wc, wc} + cswap(v) * (f32x2){-wsv, wsv};
        a[base + j]        = u + vw;
        a[base + j + half] = u - vw;
      }
    }
  }
}

// cross-quad 4-point DFT; D1 = first dpp, D2 = second.
template<int D1, int D2>
__device__ __forceinline__ f32x2 cross4(f32x2 z, f32x2 sgn, f32x2 r, bool psel, bool qsw) {
  f32x2 w  = dpp2<D1>(z);
  f32x2 z1 = w + sgn * z;
  f32x2 w2 = dpp2<D2>(z1);
  f32x2 p  = psel ? w2 : z1;
  f32x2 qb = psel ? z1 : w2;
  f32x2 q  = qsw ? cswap(qb) : qb;
  return p + q * r;
}

struct CrossCtl {
  f32x2 sgnF, rF, sgnI, rI;
  bool s1, s2;
};

// 64-point FFT across a quad (thread holds 16 elems). Forward output reg i
// holds freq k = k2 + 4*i; inverse consumes that, returns natural.
template<int SIGN>
__device__ __forceinline__ void fft64v(f32x2* a, const CrossCtl& c,
                                       const float* twc, const float* tws) {
  if (SIGN < 0) {
#pragma unroll
    for (int i = 0; i < 16; ++i) a[i] = cross4<DPP_XOR2, DPP_XOR1>(a[i], c.sgnF, c.rF, c.s1, c.s2);
#pragma unroll
    for (int i = 0; i < 16; ++i) {    // * W64^{-n1*k2} = (cos - i sin)
      float cc = twc[i], ss = tws[i];
      a[i] = a[i] * (f32x2){cc, cc} + cswap(a[i]) * (f32x2){ss, -ss};
    }
    fft16v<-1>(a);
  } else {
    fft16v<1>(a);
#pragma unroll
    for (int i = 0; i < 16; ++i) {    // * W64^{+n1*k2}
      float cc = twc[i], ss = tws[i];
      a[i] = a[i] * (f32x2){cc, cc} + cswap(a[i]) * (f32x2){-ss, ss};
    }
#pragma unroll
    for (int i = 0; i < 16; ++i) a[i] = cross4<DPP_XOR1, DPP_XOR2>(a[i], c.sgnI, c.rI, c.s2, c.s1);
  }
}

// scale = sA * rsqrt(cB*q + cC)
__device__ __forceinline__ void reactv(f32x2* a, float sA, float cB, float cC) {
#pragma unroll
  for (int i = 0; i < 16; ++i) {
    float q = fmaf(a[i].x, a[i].x, a[i].y * a[i].y);
    float s = sA * rsqrtf(fmaf(cB, q, cC));
    a[i] *= (f32x2){s, s};
  }
}

// ---------------------------------------------------------------------------

__global__ void zero_kernel(float* p, int n) {
  int i = blockIdx.x * blockDim.x + threadIdx.x;
  if (i < n) p[i] = 0.f;
}

__global__ __launch_bounds__(256) void convert_w_kernel(
    const float* __restrict__ W, _Float16* __restrict__ Wh) {
  int i = (blockIdx.x * 256 + threadIdx.x) * 8;   // 512*1024 / 8 = 65536 threads
  float4 v0 = *(const float4*)&W[i];
  float4 v1 = *(const float4*)&W[i + 4];
  half8 h = { (_Float16)v0.x, (_Float16)v0.y, (_Float16)v0.z, (_Float16)v0.w,
              (_Float16)v1.x, (_Float16)v1.y, (_Float16)v1.z, (_Float16)v1.w };
  *(half8*)&Wh[i] = h;
}

__global__ __launch_bounds__(256) void transpose_pool_kernel(
    const float* __restrict__ x, float* __restrict__ xT, float* __restrict__ pooled) {
  __shared__ float tile[64][65];
  const int n0 = blockIdx.x * 64, d0 = blockIdx.y * 64, b = blockIdx.z;
  const int t = threadIdx.x;
  const int tc = t & 63, tr = t >> 6;
  const float* xp = x + ((size_t)b * NTOK + n0) * D_INNER + d0;
#pragma unroll
  for (int i = 0; i < 16; ++i) {
    int nl = tr + i * 4;
    tile[nl][tc] = xp[(size_t)nl * D_INNER + tc];
  }
  __syncthreads();
  float* xo = xT + ((size_t)b * D_INNER + d0) * NTOK + n0;
#pragma unroll
  for (int i = 0; i < 16; ++i) {
    int dl = tr + i * 4;
    xo[(size_t)dl * NTOK + tc] = tile[tc][dl];
  }
  if (t < 64) {
    float s = 0.f;
#pragma unroll
    for (int n = 0; n < 64; ++n) s += tile[n][t];
    atomicAdd(&pooled[b * D_INNER + d0 + t], s);
  }
}

__global__ __launch_bounds__(256) void gamma_kernel(
    const float* __restrict__ pooled, const float* __restrict__ Wg,
    const float* __restrict__ bg, const float* __restrict__ log_base,
    float* __restrict__ gamma) {
  int t = blockIdx.x * 256 + threadIdx.x;       // 0..4095
  int b = t >> 9, j = t & 511;
  const float* pr = pooled + b * D_INNER;
  const float* wr = Wg + (size_t)j * D_INNER;
  float acc = 0.f;
#pragma unroll 4
  for (int d = 0; d < D_INNER; ++d) acc = fmaf(pr[d], wr[d], acc);
  float z = acc * (1.f / 4096.f) + bg[j] + log_base[j];
  float sp = fmaxf(z, 0.f) + log1pf(expf(-fabsf(z)));
  gamma[t] = fminf(sp, 0.35f);
}

// One 64x64 plane per block. Outputs fp16 planes S[b][k][n], k=d Re, 512+d Im.
__global__ __launch_bounds__(256, 4) void plane_kernel(
    const float* __restrict__ xT, const float* __restrict__ gamma,
    const float* __restrict__ alpha_raw, const float* __restrict__ beta_raw,
    const int* __restrict__ kstep_p, _Float16* __restrict__ S) {
  __shared__ f32x2 T[64 * 65];
  __shared__ f32x2 P[64];
  const int blk = blockIdx.x;          // b*512 + d
  const int bb = blk >> 9, d = blk & 511;
  const int tid = threadIdx.x;
  const int lb = tid & 3;
  const int rr = tid >> 2;

  int ks = kstep_p[0]; if (ks < 1) ks = 1;
  const float dt  = 1.0f / (float)ks;
  const float dtr = 0.5f * dt;
  const float a2 = 2.0f * 0.25f * tanhf(alpha_raw[d]);
  float zb = beta_raw[d];
  const float b2 = 2.0f * (fmaxf(zb, 0.f) + log1pf(expf(-fabsf(zb))) + 1e-4f);

  _Float16* Sre = S + ((size_t)(bb * 1024 + d)) * NTOK + rr * 64 + lb * 16;
  _Float16* Sim = S + ((size_t)(bb * 1024 + 512 + d)) * NTOK + rr * 64 + lb * 16;

  // Provably-zero channels: a2 <= -1e-6 -> denom<0 -> clamp -> q_new=0 -> psi=0.
  if (a2 <= -1e-6f) {
    half8 z = {};
    *(half8*)&Sre[0] = z; *(half8*)&Sre[8] = z;
    *(half8*)&Sim[0] = z; *(half8*)&Sim[8] = z;
    return;
  }

  // reaction constants: half-step and full-step (exact flow composition)
  float sAh, cBh, cCh, sAf, cBf, cCf;
  if (a2 < 1e-6f) {
    sAh = 1.f; cBh = b2 * dtr; cCh = 1.f;
    sAf = 1.f; cBf = b2 * dt;  cCf = 1.f;
  } else {
    float exh = expf(-a2 * dtr);
    float exf = exh * exh;
    float sq = sqrtf(a2);
    sAh = sq; cBh = b2 * (1.f - exh); cCh = a2 * exh;
    sAf = sq; cBf = b2 * (1.f - exf); cCf = a2 * exf;
  }
  const float cg = dt * gamma[(bb << 9) + d];

  const float TWO_PI_64 = 6.283185307179586f / 64.0f;
  if (tid < 64) {
    float e = 2.0f * cosf(TWO_PI_64 * (float)tid) - 2.0f;
    float sv, cv; sincosf(cg * e, &sv, &cv);
    P[tid] = (f32x2){cv * 0.015625f, sv * 0.015625f};   // 1/64 per dim
  }
  const int k2 = (lb == 1) ? 2 : ((lb == 2) ? 1 : lb);  // qmap[lb]

  CrossCtl ctl;
  {
    const bool s1 = lb & 1, s2 = (lb & 2) != 0;
    const f32x2 ONE = {1.f, 1.f}, MONE = {-1.f, -1.f};
    ctl.s1 = s1; ctl.s2 = s2;
    ctl.sgnF = s2 ? MONE : ONE;
    ctl.sgnI = s1 ? MONE : ONE;
    ctl.rF = s2 ? (s1 ? (f32x2){-1.f, 1.f} : (f32x2){1.f, -1.f}) : (s1 ? MONE : ONE);
    ctl.rI = s1 ? (s2 ? (f32x2){1.f, -1.f} : (f32x2){-1.f, 1.f}) : (s2 ? MONE : ONE);
  }

  float twc[16], tws[16];
  {
    float c1, s1v; sincosf(TWO_PI_64 * (float)k2, &s1v, &c1);
    twc[0] = 1.f; tws[0] = 0.f;
#pragma unroll
    for (int i = 1; i < 16; ++i) {
      float pc = twc[i-1], ps = tws[i-1];
      twc[i] = pc * c1 - ps * s1v;
      tws[i] = ps * c1 + pc * s1v;
    }
  }

  f32x2 a[16];
  const float* px = xT + (size_t)blk * NTOK + rr * 64 + lb * 16;
#pragma unroll
  for (int i = 0; i < 4; ++i) {
    float4 v = *(const float4*)(px + i * 4);
    a[i*4+0] = (f32x2){v.x, 0.f}; a[i*4+1] = (f32x2){v.y, 0.f};
    a[i*4+2] = (f32x2){v.z, 0.f}; a[i*4+3] = (f32x2){v.w, 0.f};
  }
  __syncthreads();   // P ready
  const f32x2 pc = P[rr];

  reactv(a, sAh, cBh, cCh);
  for (int step = 0; ; ) {
    fft64v<-1>(a, ctl, twc, tws);                 // row FFT
    __syncthreads();
#pragma unroll
    for (int i = 0; i < 16; ++i)                  // store at true kx
      T[rr * 65 + (k2 + 4 * i)] = a[i];
    __syncthreads();
#pragma unroll
    for (int i = 0; i < 16; ++i)                  // col layout, natural y
      a[i] = T[(lb * 16 + i) * 65 + rr];
    fft64v<-1>(a, ctl, twc, tws);                 // col FFT
#pragma unroll
    for (int i = 0; i < 16; ++i)                  // phase: kx=rr, ky=k2+4i
      a[i] = cmulv(a[i], cmulv(P[k2 + 4 * i], pc));
    fft64v<1>(a, ctl, twc, tws);                  // col inverse
    __syncthreads();
#pragma unroll
    for (int i = 0; i < 16; ++i)
      T[(lb * 16 + i) * 65 + rr] = a[i];
    __syncthreads();
#pragma unroll
    for (int i = 0; i < 16; ++i)
      a[i] = T[rr * 65 + (k2 + 4 * i)];
    fft64v<1>(a, ctl, twc, tws);                  // row inverse
    if (++step == ks) break;
    reactv(a, sAf, cBf, cCf);                     // merged double half-step
  }
  reactv(a, sAh, cBh, cCh);

  half8 hr0, hr1, hi0, hi1;
#pragma unroll
  for (int i = 0; i < 8; ++i) {
    hr0[i] = (_Float16)a[i].x;     hi0[i] = (_Float16)a[i].y;
    hr1[i] = (_Float16)a[8+i].x;   hi1[i] = (_Float16)a[8+i].y;
  }
  *(half8*)&Sre[0] = hr0; *(half8*)&Sre[8] = hr1;
  *(half8*)&Sim[0] = hi0; *(half8*)&Sim[8] = hi1;
}

// S[b][k][n] -> S_T[b][n][k], 64x64 fp16 tiles, XOR-swizzled LDS.
__global__ __launch_bounds__(256) void transpose_S_kernel(
    const _Float16* __restrict__ S, _Float16* __restrict__ ST) {
  __shared__ __attribute__((aligned(16))) _Float16 tile[64 * 64];
  const int n0 = blockIdx.x * 64, k0 = blockIdx.y * 64, b = blockIdx.z;
  const int t = threadIdx.x;
#pragma unroll
  for (int r = 0; r < 2; ++r) {
    int idx = r * 256 + t, kr = idx >> 3, c = idx & 7;
    half8 v = *(const half8*)&S[((size_t)b * 1024 + k0 + kr) * NTOK + n0 + c * 8];
    *(half8*)&tile[kr * 64 + ((c ^ (kr & 7)) * 8)] = v;
  }
  __syncthreads();
#pragma unroll
  for (int r = 0; r < 2; ++r) {
    int idx = r * 256 + t, nr = idx >> 3, ck = idx & 7;
    half8 v;
#pragma unroll
    for (int j = 0; j < 8; ++j) {
      int k = ck * 8 + j;
      v[j] = tile[k * 64 + (((nr >> 3) ^ (k & 7)) * 8) + (nr & 7)];
    }
    *(half8*)&ST[((size_t)b * NTOK + n0 + nr) * 1024 + k0 + ck * 8] = v;
  }
}

#define GLDS16(g, l) __builtin_amdgcn_global_load_lds( \
    (const __attribute__((address_space(1))) void*)(g), \
    (__attribute__((address_space(3))) void*)(l), 16, 0, 0)

// out[b,n,j] = sum_k Wh[j,k]*ST[b,n,k] + x[b,n,j]*Dp[j]
// 128n x 128j, BK=32, f16 MFMA; global_load_lds staging, 2-phase dbuf,
// one barrier per K-step.
__global__ __launch_bounds__(256) void out_gemm_f16(
    const _Float16* __restrict__ ST, const _Float16* __restrict__ Wh,
    const float* __restrict__ x, const float* __restrict__ Dp,
    float* __restrict__ out) {
  __shared__ __attribute__((aligned(16))) _Float16 Abuf[2][128 * 32];  // W [j][k]
  __shared__ __attribute__((aligned(16))) _Float16 Bbuf[2][128 * 32];  // S [n][k]
  const int t = threadIdx.x;
  const int n0 = blockIdx.x * 128, j0 = blockIdx.y * 128, b = blockIdx.z;
  const int w = t >> 6, l = t & 63;
  const int jw = (w & 1) * 64, nw = (w >> 1) * 64;
  const int l15 = l & 15, l4 = l >> 4;

  // staging: wave w stages rows [w*32, w*32+32) of A and B (two 16-row insts)
  const int rowg = w * 32 + (l >> 2);   // row for group 0; +16 for group 1
  const int colh = (l & 3) * 8;         // halves within 64B row
  const _Float16* gA0 = Wh + (size_t)(j0 + rowg) * 1024 + colh;
  const _Float16* gB0 = ST + ((size_t)b * NTOK + n0 + rowg) * 1024 + colh;
  const int lOff0 = rowg * 32 + colh, lOff1 = lOff0 + 16 * 32;

  auto stage = [&](int buf, int kt) {
    const int ko = kt * 32;
    GLDS16(gA0 + ko,               &Abuf[buf][lOff0]);
    GLDS16(gA0 + ko + 16 * 1024,   &Abuf[buf][lOff1]);
    GLDS16(gB0 + ko,               &Bbuf[buf][lOff0]);
    GLDS16(gB0 + ko + 16 * 1024,   &Bbuf[buf][lOff1]);
  };

  f32x4 acc[4][4] = {};
  stage(0, 0);
  __syncthreads();                      // drains vmcnt, tile 0 ready
  int cur = 0;
  for (int kt = 0; kt < 32; ++kt) {
    if (kt + 1 < 32) stage(cur ^ 1, kt + 1);
    half8 af[4], bf[4];
#pragma unroll
    for (int ff = 0; ff < 4; ++ff) {
      af[ff] = *(const half8*)&Abuf[cur][(jw + ff * 16 + l15) * 32 + l4 * 8];
      bf[ff] = *(const half8*)&Bbuf[cur][(nw + ff * 16 + l15) * 32 + l4 * 8];
    }
#pragma unroll
    for (int jf = 0; jf < 4; ++jf)
#pragma unroll
      for (int nf = 0; nf < 4; ++nf)
        acc[jf][nf] = __builtin_amdgcn_mfma_f32_16x16x32_f16(af[jf], bf[nf], acc[jf][nf], 0, 0, 0);
    __syncthreads();                    // drains next-tile loads + guards reuse
    cur ^= 1;
  }

#pragma unroll
  for (int jf = 0; jf < 4; ++jf) {
#pragma unroll
    for (int nf = 0; nf < 4; ++nf) {
      int jr4 = j0 + jw + jf * 16 + l4 * 4;
      int n   = n0 + nw + nf * 16 + l15;
      const float* xrow = x + ((size_t)b * NTOK + n) * D_INNER + jr4;
      float* orow = out + ((size_t)b * NTOK + n) * D_INNER + jr4;
      float4 xv = *(const float4*)xrow;
      float4 dv = *(const float4*)&Dp[jr4];
      float4 o;
      o.x = acc[jf][nf][0] + xv.x * dv.x;
      o.y = acc[jf][nf][1] + xv.y * dv.y;
      o.z = acc[jf][nf][2] + xv.z * dv.z;
      o.w = acc[jf][nf][3] + xv.w * dv.w;
      *(float4*)orow = o;
    }
  }
}

// ---------------------------------------------------------------------------

extern "C" void kernel_launch(void* const* d_in, const int* in_sizes, int n_in,
                              void* d_out, int out_size, void* d_ws, size_t ws_size,
                              hipStream_t stream) {
  const float* x         = (const float*)d_in[0];
  const float* Wg        = (const float*)d_in[1];
  const float* bg        = (const float*)d_in[2];
  const float* log_base  = (const float*)d_in[3];
  const float* alpha_raw = (const float*)d_in[4];
  const float* beta_raw  = (const float*)d_in[5];
  const float* Wout      = (const float*)d_in[6];
  const float* Dparam    = (const float*)d_in[7];
  const int*   kstep     = (const int*)d_in[8];
  float* out = (float*)d_out;

  char* ws = (char*)d_ws;
  float*    xT  = (float*)ws;                         // [B,512,4096] f32, 64 MiB
  _Float16* S   = (_Float16*)(ws + 67108864);         // [B,1024,4096] fp16, 64 MiB
  _Float16* STr = (_Float16*)ws;                      // [B,4096,1024] fp16, overlays xT
  float* pooled = (float*)(ws + 134217728);           // [B,512]
  float* gamma  = pooled + 8 * D_INNER;               // [B,512]
  _Float16* Wh  = (_Float16*)(ws + 134217728 + 65536);// [512,1024] fp16, 1 MiB

  zero_kernel<<<16, 256, 0, stream>>>(pooled, 8 * D_INNER);
  convert_w_kernel<<<256, 256, 0, stream>>>(Wout, Wh);
  transpose_pool_kernel<<<dim3(64, 8, 8), 256, 0, stream>>>(x, xT, pooled);
  gamma_kernel<<<16, 256, 0, stream>>>(pooled, Wg, bg, log_base, gamma);
  plane_kernel<<<4096, 256, 0, stream>>>(xT, gamma, alpha_raw, beta_raw, kstep, S);
  transpose_S_kernel<<<dim3(64, 16, 8), 256, 0, stream>>>(S, STr);
  out_gemm_f16<<<dim3(32, 4, 8), 256, 0, stream>>>(STr, Wh, x, Dparam, out);
}